// Round 17
// baseline (100.021 us; speedup 1.0000x reference)
//
#include <hip/hip_runtime.h>
#include <stdint.h>

#define Bq 4
#define Sq 4096
#define DIN 512
#define Uq 128
#define Mq (Bq * Sq)
#define LOG2E 1.44269504f

typedef __attribute__((ext_vector_type(8))) _Float16 f16x8;
typedef __attribute__((ext_vector_type(4))) float f32x4;
typedef __attribute__((ext_vector_type(16))) float f32x16;
typedef unsigned short u16;

__device__ __forceinline__ u16 f2h(float f) {
  union { _Float16 h; u16 u; } v;
  v.h = (_Float16)f;
  return v.u;
}
__device__ __forceinline__ float h2f(u16 u) {
  union { u16 u; _Float16 h; } v;
  v.u = u;
  return (float)v.h;
}
__device__ __forceinline__ unsigned pk2(float a, float b) {
  return __builtin_bit_cast(unsigned, __builtin_amdgcn_cvt_pkrtz(a, b));
}
__device__ __forceinline__ void gl_lds16(const void* g, void* l) {
  __builtin_amdgcn_global_load_lds(
      (const __attribute__((address_space(1))) unsigned int*)g,
      (__attribute__((address_space(3))) unsigned int*)l, 16, 0, 0);
}
__device__ __forceinline__ float xmax32(float v) { return fmaxf(v, __shfl_xor(v, 32)); }
__device__ __forceinline__ float xsum32(float v) { return v + __shfl_xor(v, 32); }

// raw v_exp_f32 (args bounded: <= +8 by defer-max; large-negative underflows to 0)
#if defined(__has_builtin) && __has_builtin(__builtin_amdgcn_exp2f)
#define EXP2(x) __builtin_amdgcn_exp2f(x)
#else
#define EXP2(x) exp2f(x)
#endif

// ---------------- W transpose: W[512][128] f32 -> Wt[128][512] fp16 ----------------
__global__ __launch_bounds__(256) void wt_kernel(const float* __restrict__ Wqp,
                                                 const float* __restrict__ Wkp,
                                                 const float* __restrict__ Wvp,
                                                 u16* __restrict__ wt) {
  int idx = blockIdx.x * 256 + threadIdx.x;
  int z = idx >> 16, r = idx & 65535;
  int n = r >> 9, k = r & 511;
  const float* W = (z == 0) ? Wqp : ((z == 1) ? Wkp : Wvp);
  wt[idx] = f2h(W[k * Uq + n]);
}

// ------------- fused QKV projection + ReLU -> fp16 (q scaled by log2e) -------------
// 32-row m-tiles, grid 512, 4 waves; wave w owns 6 global f-cols gf in [6w,6w+6).
// NO LDS, NO barriers: each wave loads its own X A-frags direct from global (L2-hot,
// 4x tile re-read is ~16KB/step) + reg-prefetches X and W one step ahead.
__global__ __launch_bounds__(256, 2) void proj_kernel(const float* __restrict__ X,
                                                      const u16* __restrict__ Wt,
                                                      const float* __restrict__ bqp,
                                                      const float* __restrict__ bkp,
                                                      const float* __restrict__ bvp,
                                                      u16* __restrict__ qkv) {
  const int mbase = blockIdx.x * 32;
  const int tid = threadIdx.x;
  const int wid = tid >> 6, lane = tid & 63;
  const int lo = lane & 15, g = lane >> 4;

  f32x4 acc[2][6];
#pragma unroll
  for (int mg = 0; mg < 2; ++mg)
#pragma unroll
    for (int fi = 0; fi < 6; ++fi) acc[mg][fi] = (f32x4){0.f, 0.f, 0.f, 0.f};

  // direct global A-frag pointers: rows {mbase+lo, mbase+16+lo}, cols 8g..8g+7 (+32/step)
  const float* xp0 = X + (size_t)(mbase + lo) * DIN + 8 * g;
  const float* xp1 = xp0 + (size_t)16 * DIN;
  float4 xa0 = *(const float4*)xp0;
  float4 xb0 = *(const float4*)(xp0 + 4);
  float4 xa1 = *(const float4*)xp1;
  float4 xb1 = *(const float4*)(xp1 + 4);

  const u16* wp[6];
#pragma unroll
  for (int fi = 0; fi < 6; ++fi) {
    const int gf = 6 * wid + fi;
    const int R = (gf >> 3) * 128 + (gf & 7) * 16 + lo;
    wp[fi] = Wt + (size_t)R * 512 + 8 * g;
  }
  f16x8 bw[6];
#pragma unroll
  for (int fi = 0; fi < 6; ++fi) bw[fi] = *(const f16x8*)(wp[fi]);

  for (int step = 0; step < 16; ++step) {
    // pack current X frags (RTZ pack, 1 op per pair)
    union { unsigned u[4]; f16x8 v; } w0, w1;
    w0.u[0] = pk2(xa0.x, xa0.y); w0.u[1] = pk2(xa0.z, xa0.w);
    w0.u[2] = pk2(xb0.x, xb0.y); w0.u[3] = pk2(xb0.z, xb0.w);
    w1.u[0] = pk2(xa1.x, xa1.y); w1.u[1] = pk2(xa1.z, xa1.w);
    w1.u[2] = pk2(xb1.x, xb1.y); w1.u[3] = pk2(xb1.z, xb1.w);
    f16x8 a0 = w0.v, a1 = w1.v;

    if (step < 15) {   // prefetch next X frags (fly under the MFMAs)
      const float* n0 = xp0 + (step + 1) * 32;
      const float* n1 = xp1 + (step + 1) * 32;
      xa0 = *(const float4*)n0;
      xb0 = *(const float4*)(n0 + 4);
      xa1 = *(const float4*)n1;
      xb1 = *(const float4*)(n1 + 4);
    }
#pragma unroll
    for (int fi = 0; fi < 6; ++fi) {
      acc[0][fi] = __builtin_amdgcn_mfma_f32_16x16x32_f16(a0, bw[fi], acc[0][fi], 0, 0, 0);
      acc[1][fi] = __builtin_amdgcn_mfma_f32_16x16x32_f16(a1, bw[fi], acc[1][fi], 0, 0, 0);
    }
    if (step < 15) {   // prefetch next W frags
#pragma unroll
      for (int fi = 0; fi < 6; ++fi)
        bw[fi] = *(const f16x8*)(wp[fi] + (step + 1) * 32);
    }
  }

  // C/D: col = lane&15, row (m) = 4*(lane>>4)+reg
#pragma unroll
  for (int fi = 0; fi < 6; ++fi) {
    const int gf = 6 * wid + fi;
    const int z = gf >> 3, fl = gf & 7;
    const float* bias = (z == 0) ? bqp : ((z == 1) ? bkp : bvp);
    const float bb = bias[fl * 16 + lo];
    if (z < 2) {
      u16* dst = qkv + (size_t)z * Mq * Uq;
      const float qs = (z == 0) ? LOG2E : 1.0f;
#pragma unroll
      for (int mg = 0; mg < 2; ++mg)
#pragma unroll
        for (int r = 0; r < 4; ++r) {
          const int m = mbase + 16 * mg + 4 * g + r;
          dst[(size_t)m * Uq + fl * 16 + lo] = f2h(fmaxf(acc[mg][fi][r] + bb, 0.f) * qs);
        }
    } else {
      u16* vT = qkv + (size_t)2 * Mq * Uq;   // vT[batch][n][s]
      const int n = fl * 16 + lo;
#pragma unroll
      for (int mg = 0; mg < 2; ++mg) {
        const int m0 = mbase + 16 * mg + 4 * g;
        const int bb_ = m0 >> 12, s0 = m0 & (Sq - 1);
        ushort4 pv = make_ushort4(f2h(fmaxf(acc[mg][fi][0] + bb, 0.f)),
                                  f2h(fmaxf(acc[mg][fi][1] + bb, 0.f)),
                                  f2h(fmaxf(acc[mg][fi][2] + bb, 0.f)),
                                  f2h(fmaxf(acc[mg][fi][3] + bb, 0.f)));
        *(ushort4*)(vT + (size_t)bb_ * Uq * Sq + (size_t)n * Sq + s0) = pv;
      }
    }
  }
}

// ---------------- flash attention partials (32x32 swapped QK^T, lane-local softmax) ----
// 4 warps x 32 q-rows (128 rows/block). KBLK=64. nsplit=4, grid 512 (best-known, R11).
// Counted vmcnt(4) at B1; raw v_exp_f32 for all exp2 (R15/R16's proven attn).
__global__ __launch_bounds__(256, 2) void attn_kernel(const u16* __restrict__ qkv,
                                                      u16* __restrict__ op,
                                                      float2* __restrict__ mlp,
                                                      int kvlen) {
  const int nb = gridDim.x;                  // 128 * nsplit
  const int bid = blockIdx.x;
  const int xcd = bid & 7, idx = bid >> 3;
  const int b = xcd >> 1;                    // batch pinned to 2 XCDs
  const int within = (xcd & 1) * (nb >> 3) + idx;   // [0, 32*nsplit)
  const int split = within >> 5, qblk = within & 31;
  const int kv0 = split * kvlen;
  const int kvrem = Sq - kv0;
  const int nit = ((kvrem < kvlen) ? kvrem : kvlen) >> 6;

  const int tid = threadIdx.x;
  const int wid = tid >> 6, lane = tid & 63;
  const int l32 = lane & 31, hi = lane >> 5;

  const u16* kbase = qkv + (size_t)Mq * Uq + (size_t)b * Sq * Uq;
  const u16* vbase = qkv + (size_t)2 * Mq * Uq + (size_t)b * Uq * Sq;

  __shared__ __align__(16) unsigned char kt[16384];       // 64 x 256B, XOR-swizzled
  __shared__ __align__(16) unsigned char vt[16384];       // 128 x 128B, XOR-swizzled
  __shared__ __align__(16) unsigned char plds[4][4096];   // per-wave P: 32 x 128B, swz
  __shared__ float smx[4][32];                            // per-warp broadcasts

  // K reg-staging: wave w covers rows [16w,16w+16); lane -> 4 x 16B
  const int s4 = lane >> 4, j16 = lane & 15;
  const char* kg = (const char*)kbase + (size_t)(kv0 + 16 * wid) * 256 + 16 * lane;
  const int kwo0 = (16 * wid + 0 + s4) * 256 + ((j16 ^ ((0 + s4) & 7)) << 4);
  const int kwo1 = (16 * wid + 4 + s4) * 256 + ((j16 ^ ((4 + s4) & 7)) << 4);
  const int kwo2 = (16 * wid + 8 + s4) * 256 + ((j16 ^ ((8 + s4) & 7)) << 4);
  const int kwo3 = (16 * wid + 12 + s4) * 256 + ((j16 ^ ((12 + s4) & 7)) << 4);

  // V gl_lds: wave w covers vT rows [32w,32w+32); source pre-swizzled
  const int s8 = lane >> 3, j8 = lane & 7;
  const int vo = s8 * 8192 + ((j8 ^ s8) << 4);
  const char* vgp = (const char*)vbase + (size_t)kv0 * 2 + (size_t)wid * 262144 + vo;
  char* const vl = (char*)vt + wid * 4096;

#define VSTAGE() do {                       \
    gl_lds16(vgp,          vl);             \
    gl_lds16(vgp + 65536,  vl + 1024);      \
    gl_lds16(vgp + 131072, vl + 2048);      \
    gl_lds16(vgp + 196608, vl + 3072);      \
  } while (0)
#define KLOAD() do {                        \
    ka0 = *(const uint4*)(kg + 0);          \
    ka1 = *(const uint4*)(kg + 1024);       \
    ka2 = *(const uint4*)(kg + 2048);       \
    ka3 = *(const uint4*)(kg + 3072);       \
    kg += 16384;                            \
  } while (0)
#define KWRITE() do {                       \
    *(uint4*)(&kt[kwo0]) = ka0;             \
    *(uint4*)(&kt[kwo1]) = ka1;             \
    *(uint4*)(&kt[kwo2]) = ka2;             \
    *(uint4*)(&kt[kwo3]) = ka3;             \
  } while (0)

  // Q frags (B operand of swapped 32x32 QK^T): q = qrow, k = 16*ks + 8*hi + j
  const int qrow = b * Sq + qblk * 128 + wid * 32 + l32;
  f16x8 qf[8];
#pragma unroll
  for (int ks = 0; ks < 8; ++ks)
    qf[ks] = *(const f16x8*)(qkv + (size_t)qrow * Uq + 16 * ks + 8 * hi);

  f32x16 acc4[4];
#pragma unroll
  for (int f = 0; f < 4; ++f) acc4[f] = (f32x16){};
  float m_run = -1e30f, l_run = 0.f;
  float* const smxw = &smx[wid][0];

  // plds bases: row = q = l32 (128B, 8 chunks of 16B), chunk XOR (l32&7)
  const int q7 = l32 & 7;
  char* const plw = (char*)plds + wid * 4096 + l32 * 128 + 8 * hi;    // write base
  const char* const plr = (const char*)plds + wid * 4096 + l32 * 128; // read base

  uint4 ka0, ka1, ka2, ka3;

  // ---- prologue ----
  VSTAGE();
  KLOAD();
  asm volatile("s_waitcnt vmcnt(0)" ::: "memory");
  KWRITE();
  if (nit > 1) KLOAD();
  asm volatile("s_waitcnt lgkmcnt(0)" ::: "memory");
  __builtin_amdgcn_sched_barrier(0);
  __builtin_amdgcn_s_barrier();
  __builtin_amdgcn_sched_barrier(0);

  for (int it = 0; it < nit; ++it) {
    // ---- QK^T (swapped, 32x32): lane owns q = l32 (full P-row across the hi-pair) ----
    f32x16 sf0 = (f32x16){}, sf1 = (f32x16){};
    __builtin_amdgcn_s_setprio(1);
#pragma unroll
    for (int ks = 0; ks < 8; ++ks) {
      const int co = ((2 * ks + hi) ^ q7) << 4;
      f16x8 a0 = *(const f16x8*)(&kt[l32 * 256 + co]);
      f16x8 a1 = *(const f16x8*)(&kt[(32 + l32) * 256 + co]);
      sf0 = __builtin_amdgcn_mfma_f32_32x32x16_f16(a0, qf[ks], sf0, 0, 0, 0);
      sf1 = __builtin_amdgcn_mfma_f32_32x32x16_f16(a1, qf[ks], sf1, 0, 0, 0);
    }
    __builtin_amdgcn_s_setprio(0);

    // ---- lane-local softmax (log2 domain); sf reg r <-> kv = (r&3)+8*(r>>2)+4*hi ----
    float t8[8];
#pragma unroll
    for (int i = 0; i < 8; ++i)
      t8[i] = fmaxf(fmaxf(sf0[i], sf0[i + 8]), fmaxf(sf1[i], sf1[i + 8]));
#pragma unroll
    for (int i = 0; i < 4; ++i) t8[i] = fmaxf(t8[i], t8[i + 4]);
    float tmax = fmaxf(fmaxf(t8[0], t8[1]), fmaxf(t8[2], t8[3]));
    tmax = xmax32(tmax);                      // combine hi/lo halves of the q-row

    if (__any(tmax > m_run + 8.f)) {          // T13 defer-max (rare)
      const float m_new = fmaxf(m_run, tmax);
      const float sc = EXP2(m_run - m_new);
      if (lane < 32) smxw[l32] = sc;
#pragma unroll
      for (int r = 0; r < 16; ++r) {
        const float scr = smxw[(r & 3) + 8 * (r >> 2) + 4 * hi];
#pragma unroll
        for (int f = 0; f < 4; ++f) acc4[f][r] *= scr;
      }
      l_run *= sc;
      m_run = m_new;
    }

    float psum = 0.f;
    unsigned Ap[2][4], Bp[2][4];
#pragma unroll
    for (int ks2 = 0; ks2 < 2; ++ks2) {
#pragma unroll
      for (int m = 0; m < 4; ++m) {
        const float s0v = ks2 ? sf1[4 * m + 0] : sf0[4 * m + 0];
        const float s1v = ks2 ? sf1[4 * m + 1] : sf0[4 * m + 1];
        const float s2v = ks2 ? sf1[4 * m + 2] : sf0[4 * m + 2];
        const float s3v = ks2 ? sf1[4 * m + 3] : sf0[4 * m + 3];
        const float p0 = EXP2(s0v - m_run), p1 = EXP2(s1v - m_run);
        const float p2 = EXP2(s2v - m_run), p3 = EXP2(s3v - m_run);
        psum += (p0 + p1) + (p2 + p3);
        Ap[ks2][m] = pk2(p0, p1);
        Bp[ks2][m] = pk2(p2, p3);
      }
    }
    l_run += xsum32(psum);

    // ---- P refragment via per-wave swizzled LDS roundtrip ----
#pragma unroll
    for (int ks2 = 0; ks2 < 2; ++ks2)
#pragma unroll
      for (int m = 0; m < 4; ++m) {
        const int c = 4 * ks2 + m;
        *(uint2*)(plw + ((c ^ q7) << 4)) = make_uint2(Ap[ks2][m], Bp[ks2][m]);
      }
    f16x8 pa[4];
#pragma unroll
    for (int ks2 = 0; ks2 < 2; ++ks2)
#pragma unroll
      for (int kk = 0; kk < 2; ++kk)
        pa[2 * ks2 + kk] =
            *(const f16x8*)(plr + (((4 * ks2 + 2 * kk + hi) ^ q7) << 4));

    // counted drain (T4): only V(it)'s 4 gl_lds must land; K(it+1) flies under PV
    if (it + 1 < nit) asm volatile("s_waitcnt vmcnt(4)" ::: "memory");
    else              asm volatile("s_waitcnt vmcnt(0)" ::: "memory");
    __builtin_amdgcn_sched_barrier(0);
    __builtin_amdgcn_s_barrier();                      // B1: V visible, kt QK reads done
    __builtin_amdgcn_sched_barrier(0);

    // ---- PV (32x32): O[q][d] += P[q][kv] * V[kv][d] ----
    __builtin_amdgcn_s_setprio(1);
#pragma unroll
    for (int ks = 0; ks < 4; ++ks) {
#pragma unroll
      for (int f = 0; f < 4; ++f) {
        const int d = 32 * f + l32;
        f16x8 bv = *(const f16x8*)(&vt[d * 128 + (((2 * ks + hi) ^ q7) << 4)]);
        acc4[f] = __builtin_amdgcn_mfma_f32_32x32x16_f16(pa[ks], bv, acc4[f], 0, 0, 0);
      }
    }
    __builtin_amdgcn_s_setprio(0);

    if (it + 1 < nit) KWRITE();            // K(it+1): regs -> kt (auto vmcnt wait on ka)
    asm volatile("s_waitcnt lgkmcnt(0)" ::: "memory");
    __builtin_amdgcn_sched_barrier(0);
    __builtin_amdgcn_s_barrier();          // B2: kt(it+1) visible, vt PV reads done
    __builtin_amdgcn_sched_barrier(0);

    if (it + 1 < nit) {
      vgp += 128;
      VSTAGE();                            // V(it+1) flies under next QK^T+softmax
      if (it + 2 < nit) KLOAD();           // K(it+2) -> regs
    }
  }
#undef VSTAGE
#undef KLOAD
#undef KWRITE

  // ---- write NORMALIZED fp16 partials + (m,l) ----
  if (lane < 32) smxw[l32] = 1.f / l_run;   // per-q reciprocal broadcast (same-wave LDS)
  const size_t rb = (size_t)split * Mq + (size_t)b * Sq + qblk * 128 + wid * 32;
  if (lane < 32) mlp[rb + lane] = make_float2(m_run, l_run);
  u16* od = op + rb * Uq;
#pragma unroll
  for (int f = 0; f < 4; ++f)
#pragma unroll
    for (int r = 0; r < 16; ++r) {
      const int qr = (r & 3) + 8 * (r >> 2) + 4 * hi;
      od[(size_t)qr * Uq + 32 * f + l32] = f2h(acc4[f][r] * smxw[qr]);
    }
}

// ---------------- combine kv-split partials (log2 domain, fp16 normalized) ----------------
__global__ __launch_bounds__(256) void combine_kernel(const u16* __restrict__ op,
                                                      const float2* __restrict__ mlp,
                                                      float* __restrict__ out,
                                                      int nsplit) {
  const int idx = blockIdx.x * 256 + threadIdx.x;
  const int q = idx >> 5, nq = idx & 31;
  float M = -1e30f;
  for (int s = 0; s < nsplit; ++s) M = fmaxf(M, mlp[(size_t)s * Mq + q].x);
  float L = 0.f;
  float ox = 0.f, oy = 0.f, oz = 0.f, ow = 0.f;
  for (int s = 0; s < nsplit; ++s) {
    const float2 ml = mlp[(size_t)s * Mq + q];
    const float w = EXP2(ml.x - M) * ml.y;   // weight = exp2(m-M) * l
    L += w;
    const ushort4 v = *(const ushort4*)(op + ((size_t)s * Mq + q) * Uq + nq * 4);
    ox += w * h2f(v.x); oy += w * h2f(v.y); oz += w * h2f(v.z); ow += w * h2f(v.w);
  }
  const float inv = 1.f / L;
  *(float4*)(out + (size_t)q * Uq + nq * 4) = make_float4(ox * inv, oy * inv, oz * inv, ow * inv);
}

extern "C" void kernel_launch(void* const* d_in, const int* in_sizes, int n_in,
                              void* d_out, int out_size, void* d_ws, size_t ws_size,
                              hipStream_t stream) {
  const float* X   = (const float*)d_in[0];
  const float* Wqp = (const float*)d_in[1];
  const float* bqp = (const float*)d_in[2];
  const float* Wkp = (const float*)d_in[3];
  const float* bkp = (const float*)d_in[4];
  const float* Wvp = (const float*)d_in[5];
  const float* bvp = (const float*)d_in[6];
  float* out = (float*)d_out;

  u16* qkv = (u16*)d_ws;                                   // q(4MB) k(4MB) vT(4MB) fp16
  u16* wt  = qkv + (size_t)3 * Mq * Uq;                    // 3 x [128][512] fp16
  u16* op  = wt + 3 * 65536;                               // normalized fp16 partials

  const size_t base = (size_t)12976128;                    // qkv + wt bytes
  const size_t per  = (size_t)(Mq * Uq * 2 + Mq * 8);      // 4.19MB op + 1MB mlp
  int nsplit = 4;                                          // grid 512 = best-known (R11)
  if (ws_size < base + 4 * per) nsplit = 2;
  if (ws_size < base + 2 * per) nsplit = 1;
  float2* mlp = (float2*)(op + (size_t)nsplit * Mq * Uq);
  const int kvlen = Sq / nsplit;

  wt_kernel<<<768, 256, 0, stream>>>(Wqp, Wkp, Wvp, wt);
  proj_kernel<<<Mq / 32, 256, 0, stream>>>(X, wt, bqp, bkp, bvp, qkv);
  attn_kernel<<<128 * nsplit, 256, 0, stream>>>(qkv, op, mlp, kvlen);
  combine_kernel<<<(Mq * 32) / 256, 256, 0, stream>>>(op, mlp, out, nsplit);
}

// Round 18
// 93.355 us; speedup vs baseline: 1.0714x; 1.0714x over previous
//
#include <hip/hip_runtime.h>
#include <stdint.h>

#define Bq 4
#define Sq 4096
#define DIN 512
#define Uq 128
#define Mq (Bq * Sq)
#define LOG2E 1.44269504f

typedef __attribute__((ext_vector_type(8))) _Float16 f16x8;
typedef __attribute__((ext_vector_type(4))) float f32x4;
typedef __attribute__((ext_vector_type(16))) float f32x16;
typedef unsigned short u16;

__device__ __forceinline__ u16 f2h(float f) {
  union { _Float16 h; u16 u; } v;
  v.h = (_Float16)f;
  return v.u;
}
__device__ __forceinline__ float h2f(u16 u) {
  union { u16 u; _Float16 h; } v;
  v.u = u;
  return (float)v.h;
}
__device__ __forceinline__ unsigned pk2(float a, float b) {
  return __builtin_bit_cast(unsigned, __builtin_amdgcn_cvt_pkrtz(a, b));
}
__device__ __forceinline__ void gl_lds16(const void* g, void* l) {
  __builtin_amdgcn_global_load_lds(
      (const __attribute__((address_space(1))) unsigned int*)g,
      (__attribute__((address_space(3))) unsigned int*)l, 16, 0, 0);
}
__device__ __forceinline__ float xmax32(float v) { return fmaxf(v, __shfl_xor(v, 32)); }
__device__ __forceinline__ float xsum32(float v) { return v + __shfl_xor(v, 32); }

// raw v_exp_f32 (args bounded: <= +8 by defer-max; large-negative underflows to 0)
#if defined(__has_builtin) && __has_builtin(__builtin_amdgcn_exp2f)
#define EXP2(x) __builtin_amdgcn_exp2f(x)
#else
#define EXP2(x) exp2f(x)
#endif

// ---------------- W transpose: W[512][128] f32 -> Wt[128][512] fp16 ----------------
__global__ __launch_bounds__(256) void wt_kernel(const float* __restrict__ Wqp,
                                                 const float* __restrict__ Wkp,
                                                 const float* __restrict__ Wvp,
                                                 u16* __restrict__ wt) {
  int idx = blockIdx.x * 256 + threadIdx.x;
  int z = idx >> 16, r = idx & 65535;
  int n = r >> 9, k = r & 511;
  const float* W = (z == 0) ? Wqp : ((z == 1) ? Wkp : Wvp);
  wt[idx] = f2h(W[k * Uq + n]);
}

// ------------- fused QKV projection + ReLU -> fp16 (q scaled by log2e) -------------
// 32-row m-tiles, grid 512, 4 waves; wave w owns 6 global f-cols gf in [6w,6w+6).
// WHOLE 32x512 X tile staged ONCE (fp16, XOR-swizzled chunks, coalesced pair-float4
// loads) -> ONE barrier total; all 16 K-steps then run barrier-free per wave.
__global__ __launch_bounds__(256, 2) void proj_kernel(const float* __restrict__ X,
                                                      const u16* __restrict__ Wt,
                                                      const float* __restrict__ bqp,
                                                      const float* __restrict__ bkp,
                                                      const float* __restrict__ bvp,
                                                      u16* __restrict__ qkv) {
  const int mbase = blockIdx.x * 32;
  const int tid = threadIdx.x;
  const int wid = tid >> 6, lane = tid & 63;
  const int lo = lane & 15, g = lane >> 4;

  __shared__ __align__(16) unsigned char xt[32768];   // 32 rows x 64 chunks(16B), swz

  // ---- stage whole X tile: 2048 float4-pairs, iteration p = j*256 + tid ----
  // pair p -> row r = p>>6, chunk c = p&63 (8 f32 -> 8 fp16 = 16B)
#pragma unroll
  for (int j = 0; j < 8; ++j) {
    const int p = j * 256 + tid;
    const int r = p >> 6, c = p & 63;
    const float* src = X + (size_t)(mbase + r) * DIN + c * 8;
    float4 v0 = *(const float4*)src;
    float4 v1 = *(const float4*)(src + 4);
    union { unsigned u[4]; uint4 v; } w;
    w.u[0] = pk2(v0.x, v0.y); w.u[1] = pk2(v0.z, v0.w);
    w.u[2] = pk2(v1.x, v1.y); w.u[3] = pk2(v1.z, v1.w);
    *(uint4*)(&xt[r * 1024 + ((c ^ (r & 7)) << 4)]) = w.v;
  }

  f32x4 acc[2][6];
#pragma unroll
  for (int mg = 0; mg < 2; ++mg)
#pragma unroll
    for (int fi = 0; fi < 6; ++fi) acc[mg][fi] = (f32x4){0.f, 0.f, 0.f, 0.f};

  const u16* wp[6];
#pragma unroll
  for (int fi = 0; fi < 6; ++fi) {
    const int gf = 6 * wid + fi;
    const int R = (gf >> 3) * 128 + (gf & 7) * 16 + lo;
    wp[fi] = Wt + (size_t)R * 512 + 8 * g;
  }
  f16x8 bw[6];
#pragma unroll
  for (int fi = 0; fi < 6; ++fi) bw[fi] = *(const f16x8*)(wp[fi]);

  __syncthreads();   // the only barrier

  const int q7 = lo & 7;
  for (int step = 0; step < 16; ++step) {
    const int co = ((4 * step + g) ^ q7) << 4;
    f16x8 a0 = *(const f16x8*)(&xt[lo * 1024 + co]);
    f16x8 a1 = *(const f16x8*)(&xt[(16 + lo) * 1024 + co]);
#pragma unroll
    for (int fi = 0; fi < 6; ++fi) {
      acc[0][fi] = __builtin_amdgcn_mfma_f32_16x16x32_f16(a0, bw[fi], acc[0][fi], 0, 0, 0);
      acc[1][fi] = __builtin_amdgcn_mfma_f32_16x16x32_f16(a1, bw[fi], acc[1][fi], 0, 0, 0);
    }
    if (step < 15) {   // prefetch next W frags (fly under the MFMAs)
#pragma unroll
      for (int fi = 0; fi < 6; ++fi)
        bw[fi] = *(const f16x8*)(wp[fi] + (step + 1) * 32);
    }
  }

  // C/D: col = lane&15, row (m) = 4*(lane>>4)+reg
#pragma unroll
  for (int fi = 0; fi < 6; ++fi) {
    const int gf = 6 * wid + fi;
    const int z = gf >> 3, fl = gf & 7;
    const float* bias = (z == 0) ? bqp : ((z == 1) ? bkp : bvp);
    const float bb = bias[fl * 16 + lo];
    if (z < 2) {
      u16* dst = qkv + (size_t)z * Mq * Uq;
      const float qs = (z == 0) ? LOG2E : 1.0f;
#pragma unroll
      for (int mg = 0; mg < 2; ++mg)
#pragma unroll
        for (int r = 0; r < 4; ++r) {
          const int m = mbase + 16 * mg + 4 * g + r;
          dst[(size_t)m * Uq + fl * 16 + lo] = f2h(fmaxf(acc[mg][fi][r] + bb, 0.f) * qs);
        }
    } else {
      u16* vT = qkv + (size_t)2 * Mq * Uq;   // vT[batch][n][s]
      const int n = fl * 16 + lo;
#pragma unroll
      for (int mg = 0; mg < 2; ++mg) {
        const int m0 = mbase + 16 * mg + 4 * g;
        const int bb_ = m0 >> 12, s0 = m0 & (Sq - 1);
        ushort4 pv = make_ushort4(f2h(fmaxf(acc[mg][fi][0] + bb, 0.f)),
                                  f2h(fmaxf(acc[mg][fi][1] + bb, 0.f)),
                                  f2h(fmaxf(acc[mg][fi][2] + bb, 0.f)),
                                  f2h(fmaxf(acc[mg][fi][3] + bb, 0.f)));
        *(ushort4*)(vT + (size_t)bb_ * Uq * Sq + (size_t)n * Sq + s0) = pv;
      }
    }
  }
}

// ---------------- flash attention partials (32x32 swapped QK^T, lane-local softmax) ----
// 4 warps x 32 q-rows (128 rows/block). KBLK=64. nsplit=4, grid 512 (best-known, R11).
// Counted vmcnt(4) at B1; raw v_exp_f32 for all exp2 (R15/R16's proven attn).
__global__ __launch_bounds__(256, 2) void attn_kernel(const u16* __restrict__ qkv,
                                                      u16* __restrict__ op,
                                                      float2* __restrict__ mlp,
                                                      int kvlen) {
  const int nb = gridDim.x;                  // 128 * nsplit
  const int bid = blockIdx.x;
  const int xcd = bid & 7, idx = bid >> 3;
  const int b = xcd >> 1;                    // batch pinned to 2 XCDs
  const int within = (xcd & 1) * (nb >> 3) + idx;   // [0, 32*nsplit)
  const int split = within >> 5, qblk = within & 31;
  const int kv0 = split * kvlen;
  const int kvrem = Sq - kv0;
  const int nit = ((kvrem < kvlen) ? kvrem : kvlen) >> 6;

  const int tid = threadIdx.x;
  const int wid = tid >> 6, lane = tid & 63;
  const int l32 = lane & 31, hi = lane >> 5;

  const u16* kbase = qkv + (size_t)Mq * Uq + (size_t)b * Sq * Uq;
  const u16* vbase = qkv + (size_t)2 * Mq * Uq + (size_t)b * Uq * Sq;

  __shared__ __align__(16) unsigned char kt[16384];       // 64 x 256B, XOR-swizzled
  __shared__ __align__(16) unsigned char vt[16384];       // 128 x 128B, XOR-swizzled
  __shared__ __align__(16) unsigned char plds[4][4096];   // per-wave P: 32 x 128B, swz
  __shared__ float smx[4][32];                            // per-warp broadcasts

  // K reg-staging: wave w covers rows [16w,16w+16); lane -> 4 x 16B
  const int s4 = lane >> 4, j16 = lane & 15;
  const char* kg = (const char*)kbase + (size_t)(kv0 + 16 * wid) * 256 + 16 * lane;
  const int kwo0 = (16 * wid + 0 + s4) * 256 + ((j16 ^ ((0 + s4) & 7)) << 4);
  const int kwo1 = (16 * wid + 4 + s4) * 256 + ((j16 ^ ((4 + s4) & 7)) << 4);
  const int kwo2 = (16 * wid + 8 + s4) * 256 + ((j16 ^ ((8 + s4) & 7)) << 4);
  const int kwo3 = (16 * wid + 12 + s4) * 256 + ((j16 ^ ((12 + s4) & 7)) << 4);

  // V gl_lds: wave w covers vT rows [32w,32w+32); source pre-swizzled
  const int s8 = lane >> 3, j8 = lane & 7;
  const int vo = s8 * 8192 + ((j8 ^ s8) << 4);
  const char* vgp = (const char*)vbase + (size_t)kv0 * 2 + (size_t)wid * 262144 + vo;
  char* const vl = (char*)vt + wid * 4096;

#define VSTAGE() do {                       \
    gl_lds16(vgp,          vl);             \
    gl_lds16(vgp + 65536,  vl + 1024);      \
    gl_lds16(vgp + 131072, vl + 2048);      \
    gl_lds16(vgp + 196608, vl + 3072);      \
  } while (0)
#define KLOAD() do {                        \
    ka0 = *(const uint4*)(kg + 0);          \
    ka1 = *(const uint4*)(kg + 1024);       \
    ka2 = *(const uint4*)(kg + 2048);       \
    ka3 = *(const uint4*)(kg + 3072);       \
    kg += 16384;                            \
  } while (0)
#define KWRITE() do {                       \
    *(uint4*)(&kt[kwo0]) = ka0;             \
    *(uint4*)(&kt[kwo1]) = ka1;             \
    *(uint4*)(&kt[kwo2]) = ka2;             \
    *(uint4*)(&kt[kwo3]) = ka3;             \
  } while (0)

  // Q frags (B operand of swapped 32x32 QK^T): q = qrow, k = 16*ks + 8*hi + j
  const int qrow = b * Sq + qblk * 128 + wid * 32 + l32;
  f16x8 qf[8];
#pragma unroll
  for (int ks = 0; ks < 8; ++ks)
    qf[ks] = *(const f16x8*)(qkv + (size_t)qrow * Uq + 16 * ks + 8 * hi);

  f32x16 acc4[4];
#pragma unroll
  for (int f = 0; f < 4; ++f) acc4[f] = (f32x16){};
  float m_run = -1e30f, l_run = 0.f;
  float* const smxw = &smx[wid][0];

  // plds bases: row = q = l32 (128B, 8 chunks of 16B), chunk XOR (l32&7)
  const int q7 = l32 & 7;
  char* const plw = (char*)plds + wid * 4096 + l32 * 128 + 8 * hi;    // write base
  const char* const plr = (const char*)plds + wid * 4096 + l32 * 128; // read base

  uint4 ka0, ka1, ka2, ka3;

  // ---- prologue ----
  VSTAGE();
  KLOAD();
  asm volatile("s_waitcnt vmcnt(0)" ::: "memory");
  KWRITE();
  if (nit > 1) KLOAD();
  asm volatile("s_waitcnt lgkmcnt(0)" ::: "memory");
  __builtin_amdgcn_sched_barrier(0);
  __builtin_amdgcn_s_barrier();
  __builtin_amdgcn_sched_barrier(0);

  for (int it = 0; it < nit; ++it) {
    // ---- QK^T (swapped, 32x32): lane owns q = l32 (full P-row across the hi-pair) ----
    f32x16 sf0 = (f32x16){}, sf1 = (f32x16){};
    __builtin_amdgcn_s_setprio(1);
#pragma unroll
    for (int ks = 0; ks < 8; ++ks) {
      const int co = ((2 * ks + hi) ^ q7) << 4;
      f16x8 a0 = *(const f16x8*)(&kt[l32 * 256 + co]);
      f16x8 a1 = *(const f16x8*)(&kt[(32 + l32) * 256 + co]);
      sf0 = __builtin_amdgcn_mfma_f32_32x32x16_f16(a0, qf[ks], sf0, 0, 0, 0);
      sf1 = __builtin_amdgcn_mfma_f32_32x32x16_f16(a1, qf[ks], sf1, 0, 0, 0);
    }
    __builtin_amdgcn_s_setprio(0);

    // ---- lane-local softmax (log2 domain); sf reg r <-> kv = (r&3)+8*(r>>2)+4*hi ----
    float t8[8];
#pragma unroll
    for (int i = 0; i < 8; ++i)
      t8[i] = fmaxf(fmaxf(sf0[i], sf0[i + 8]), fmaxf(sf1[i], sf1[i + 8]));
#pragma unroll
    for (int i = 0; i < 4; ++i) t8[i] = fmaxf(t8[i], t8[i + 4]);
    float tmax = fmaxf(fmaxf(t8[0], t8[1]), fmaxf(t8[2], t8[3]));
    tmax = xmax32(tmax);                      // combine hi/lo halves of the q-row

    if (__any(tmax > m_run + 8.f)) {          // T13 defer-max (rare)
      const float m_new = fmaxf(m_run, tmax);
      const float sc = EXP2(m_run - m_new);
      if (lane < 32) smxw[l32] = sc;
#pragma unroll
      for (int r = 0; r < 16; ++r) {
        const float scr = smxw[(r & 3) + 8 * (r >> 2) + 4 * hi];
#pragma unroll
        for (int f = 0; f < 4; ++f) acc4[f][r] *= scr;
      }
      l_run *= sc;
      m_run = m_new;
    }

    float psum = 0.f;
    unsigned Ap[2][4], Bp[2][4];
#pragma unroll
    for (int ks2 = 0; ks2 < 2; ++ks2) {
#pragma unroll
      for (int m = 0; m < 4; ++m) {
        const float s0v = ks2 ? sf1[4 * m + 0] : sf0[4 * m + 0];
        const float s1v = ks2 ? sf1[4 * m + 1] : sf0[4 * m + 1];
        const float s2v = ks2 ? sf1[4 * m + 2] : sf0[4 * m + 2];
        const float s3v = ks2 ? sf1[4 * m + 3] : sf0[4 * m + 3];
        const float p0 = EXP2(s0v - m_run), p1 = EXP2(s1v - m_run);
        const float p2 = EXP2(s2v - m_run), p3 = EXP2(s3v - m_run);
        psum += (p0 + p1) + (p2 + p3);
        Ap[ks2][m] = pk2(p0, p1);
        Bp[ks2][m] = pk2(p2, p3);
      }
    }
    l_run += xsum32(psum);

    // ---- P refragment via per-wave swizzled LDS roundtrip ----
#pragma unroll
    for (int ks2 = 0; ks2 < 2; ++ks2)
#pragma unroll
      for (int m = 0; m < 4; ++m) {
        const int c = 4 * ks2 + m;
        *(uint2*)(plw + ((c ^ q7) << 4)) = make_uint2(Ap[ks2][m], Bp[ks2][m]);
      }
    f16x8 pa[4];
#pragma unroll
    for (int ks2 = 0; ks2 < 2; ++ks2)
#pragma unroll
      for (int kk = 0; kk < 2; ++kk)
        pa[2 * ks2 + kk] =
            *(const f16x8*)(plr + (((4 * ks2 + 2 * kk + hi) ^ q7) << 4));

    // counted drain (T4): only V(it)'s 4 gl_lds must land; K(it+1) flies under PV
    if (it + 1 < nit) asm volatile("s_waitcnt vmcnt(4)" ::: "memory");
    else              asm volatile("s_waitcnt vmcnt(0)" ::: "memory");
    __builtin_amdgcn_sched_barrier(0);
    __builtin_amdgcn_s_barrier();                      // B1: V visible, kt QK reads done
    __builtin_amdgcn_sched_barrier(0);

    // ---- PV (32x32): O[q][d] += P[q][kv] * V[kv][d] ----
    __builtin_amdgcn_s_setprio(1);
#pragma unroll
    for (int ks = 0; ks < 4; ++ks) {
#pragma unroll
      for (int f = 0; f < 4; ++f) {
        const int d = 32 * f + l32;
        f16x8 bv = *(const f16x8*)(&vt[d * 128 + (((2 * ks + hi) ^ q7) << 4)]);
        acc4[f] = __builtin_amdgcn_mfma_f32_32x32x16_f16(pa[ks], bv, acc4[f], 0, 0, 0);
      }
    }
    __builtin_amdgcn_s_setprio(0);

    if (it + 1 < nit) KWRITE();            // K(it+1): regs -> kt (auto vmcnt wait on ka)
    asm volatile("s_waitcnt lgkmcnt(0)" ::: "memory");
    __builtin_amdgcn_sched_barrier(0);
    __builtin_amdgcn_s_barrier();          // B2: kt(it+1) visible, vt PV reads done
    __builtin_amdgcn_sched_barrier(0);

    if (it + 1 < nit) {
      vgp += 128;
      VSTAGE();                            // V(it+1) flies under next QK^T+softmax
      if (it + 2 < nit) KLOAD();           // K(it+2) -> regs
    }
  }
#undef VSTAGE
#undef KLOAD
#undef KWRITE

  // ---- write NORMALIZED fp16 partials + (m,l) ----
  if (lane < 32) smxw[l32] = 1.f / l_run;   // per-q reciprocal broadcast (same-wave LDS)
  const size_t rb = (size_t)split * Mq + (size_t)b * Sq + qblk * 128 + wid * 32;
  if (lane < 32) mlp[rb + lane] = make_float2(m_run, l_run);
  u16* od = op + rb * Uq;
#pragma unroll
  for (int f = 0; f < 4; ++f)
#pragma unroll
    for (int r = 0; r < 16; ++r) {
      const int qr = (r & 3) + 8 * (r >> 2) + 4 * hi;
      od[(size_t)qr * Uq + 32 * f + l32] = f2h(acc4[f][r] * smxw[qr]);
    }
}

// ---------------- combine kv-split partials (log2 domain, fp16 normalized) ----------------
__global__ __launch_bounds__(256) void combine_kernel(const u16* __restrict__ op,
                                                      const float2* __restrict__ mlp,
                                                      float* __restrict__ out,
                                                      int nsplit) {
  const int idx = blockIdx.x * 256 + threadIdx.x;
  const int q = idx >> 5, nq = idx & 31;
  float M = -1e30f;
  for (int s = 0; s < nsplit; ++s) M = fmaxf(M, mlp[(size_t)s * Mq + q].x);
  float L = 0.f;
  float ox = 0.f, oy = 0.f, oz = 0.f, ow = 0.f;
  for (int s = 0; s < nsplit; ++s) {
    const float2 ml = mlp[(size_t)s * Mq + q];
    const float w = EXP2(ml.x - M) * ml.y;   // weight = exp2(m-M) * l
    L += w;
    const ushort4 v = *(const ushort4*)(op + ((size_t)s * Mq + q) * Uq + nq * 4);
    ox += w * h2f(v.x); oy += w * h2f(v.y); oz += w * h2f(v.z); ow += w * h2f(v.w);
  }
  const float inv = 1.f / L;
  *(float4*)(out + (size_t)q * Uq + nq * 4) = make_float4(ox * inv, oy * inv, oz * inv, ow * inv);
}

extern "C" void kernel_launch(void* const* d_in, const int* in_sizes, int n_in,
                              void* d_out, int out_size, void* d_ws, size_t ws_size,
                              hipStream_t stream) {
  const float* X   = (const float*)d_in[0];
  const float* Wqp = (const float*)d_in[1];
  const float* bqp = (const float*)d_in[2];
  const float* Wkp = (const float*)d_in[3];
  const float* bkp = (const float*)d_in[4];
  const float* Wvp = (const float*)d_in[5];
  const float* bvp = (const float*)d_in[6];
  float* out = (float*)d_out;

  u16* qkv = (u16*)d_ws;                                   // q(4MB) k(4MB) vT(4MB) fp16
  u16* wt  = qkv + (size_t)3 * Mq * Uq;                    // 3 x [128][512] fp16
  u16* op  = wt + 3 * 65536;                               // normalized fp16 partials

  const size_t base = (size_t)12976128;                    // qkv + wt bytes
  const size_t per  = (size_t)(Mq * Uq * 2 + Mq * 8);      // 4.19MB op + 1MB mlp
  int nsplit = 4;                                          // grid 512 = best-known (R11)
  if (ws_size < base + 4 * per) nsplit = 2;
  if (ws_size < base + 2 * per) nsplit = 1;
  float2* mlp = (float2*)(op + (size_t)nsplit * Mq * Uq);
  const int kvlen = Sq / nsplit;

  wt_kernel<<<768, 256, 0, stream>>>(Wqp, Wkp, Wvp, wt);
  proj_kernel<<<Mq / 32, 256, 0, stream>>>(X, wt, bqp, bkp, bvp, qkv);
  attn_kernel<<<128 * nsplit, 256, 0, stream>>>(qkv, op, mlp, kvlen);
  combine_kernel<<<(Mq * 32) / 256, 256, 0, stream>>>(op, mlp, out, nsplit);
}

// Round 19
// 87.399 us; speedup vs baseline: 1.1444x; 1.0682x over previous
//
#include <hip/hip_runtime.h>
#include <stdint.h>

#define Bq 4
#define Sq 4096
#define DIN 512
#define Uq 128
#define Mq (Bq * Sq)
#define LOG2E 1.44269504f

typedef __attribute__((ext_vector_type(8))) _Float16 f16x8;
typedef __attribute__((ext_vector_type(4))) float f32x4;
typedef __attribute__((ext_vector_type(16))) float f32x16;
typedef unsigned short u16;

__device__ __forceinline__ u16 f2h(float f) {
  union { _Float16 h; u16 u; } v;
  v.h = (_Float16)f;
  return v.u;
}
__device__ __forceinline__ float h2f(u16 u) {
  union { u16 u; _Float16 h; } v;
  v.u = u;
  return (float)v.h;
}
__device__ __forceinline__ unsigned pk2(float a, float b) {
  return __builtin_bit_cast(unsigned, __builtin_amdgcn_cvt_pkrtz(a, b));
}
__device__ __forceinline__ void gl_lds16(const void* g, void* l) {
  __builtin_amdgcn_global_load_lds(
      (const __attribute__((address_space(1))) unsigned int*)g,
      (__attribute__((address_space(3))) unsigned int*)l, 16, 0, 0);
}
__device__ __forceinline__ float xmax32(float v) { return fmaxf(v, __shfl_xor(v, 32)); }
__device__ __forceinline__ float xsum32(float v) { return v + __shfl_xor(v, 32); }

// raw v_exp_f32 (args bounded: <= +8 by defer-max; large-negative underflows to 0)
#if defined(__has_builtin) && __has_builtin(__builtin_amdgcn_exp2f)
#define EXP2(x) __builtin_amdgcn_exp2f(x)
#else
#define EXP2(x) exp2f(x)
#endif

// ---------------- W transpose: W[512][128] f32 -> Wt[128][512] fp16 ----------------
__global__ __launch_bounds__(256) void wt_kernel(const float* __restrict__ Wqp,
                                                 const float* __restrict__ Wkp,
                                                 const float* __restrict__ Wvp,
                                                 u16* __restrict__ wt) {
  int idx = blockIdx.x * 256 + threadIdx.x;
  int z = idx >> 16, r = idx & 65535;
  int n = r >> 9, k = r & 511;
  const float* W = (z == 0) ? Wqp : ((z == 1) ? Wkp : Wvp);
  wt[idx] = f2h(W[k * Uq + n]);
}

// ------------- fused QKV projection + ReLU -> fp16 (q scaled by log2e) -------------
// 32-row m-tiles, grid 512 (2 blocks/CU), 4 waves; wave w owns 6 global f-cols
// gf in [6w,6w+6). B-frags reg-prefetched one step ahead. (R14/R16's proven version.)
__global__ __launch_bounds__(256, 2) void proj_kernel(const float* __restrict__ X,
                                                      const u16* __restrict__ Wt,
                                                      const float* __restrict__ bqp,
                                                      const float* __restrict__ bkp,
                                                      const float* __restrict__ bvp,
                                                      u16* __restrict__ qkv) {
  const int mbase = blockIdx.x * 32;
  const int tid = threadIdx.x;
  const int wid = tid >> 6, lane = tid & 63;
  const int lo = lane & 15, g = lane >> 4;

  __shared__ __align__(16) u16 xt[32][40];

  f32x4 acc[2][6];
#pragma unroll
  for (int mg = 0; mg < 2; ++mg)
#pragma unroll
    for (int fi = 0; fi < 6; ++fi) acc[mg][fi] = (f32x4){0.f, 0.f, 0.f, 0.f};

  const int xrow = tid >> 2, xcc = (tid & 3) * 8;
  const float* xsrc = X + (size_t)(mbase + xrow) * DIN + xcc;
  float4 nv0, nv1;
  if (tid < 128) {
    nv0 = *(const float4*)xsrc;
    nv1 = *(const float4*)(xsrc + 4);
  }

  const u16* wp[6];
#pragma unroll
  for (int fi = 0; fi < 6; ++fi) {
    const int gf = 6 * wid + fi;
    const int R = (gf >> 3) * 128 + (gf & 7) * 16 + lo;
    wp[fi] = Wt + (size_t)R * 512 + 8 * g;
  }
  f16x8 bw[6];
#pragma unroll
  for (int fi = 0; fi < 6; ++fi) bw[fi] = *(const f16x8*)(wp[fi]);

  for (int step = 0; step < 16; ++step) {
    if (tid < 128) {
      union { u16 u[8]; uint4 v; } pk;
      pk.u[0] = f2h(nv0.x); pk.u[1] = f2h(nv0.y); pk.u[2] = f2h(nv0.z); pk.u[3] = f2h(nv0.w);
      pk.u[4] = f2h(nv1.x); pk.u[5] = f2h(nv1.y); pk.u[6] = f2h(nv1.z); pk.u[7] = f2h(nv1.w);
      *(uint4*)(&xt[xrow][xcc]) = pk.v;
    }
    __syncthreads();
    if (step < 15 && tid < 128) {
      const float* s2 = xsrc + (step + 1) * 32;
      nv0 = *(const float4*)s2;
      nv1 = *(const float4*)(s2 + 4);
    }
    f16x8 a0 = *(const f16x8*)(&xt[lo][8 * g]);
    f16x8 a1 = *(const f16x8*)(&xt[16 + lo][8 * g]);
#pragma unroll
    for (int fi = 0; fi < 6; ++fi) {
      acc[0][fi] = __builtin_amdgcn_mfma_f32_16x16x32_f16(a0, bw[fi], acc[0][fi], 0, 0, 0);
      acc[1][fi] = __builtin_amdgcn_mfma_f32_16x16x32_f16(a1, bw[fi], acc[1][fi], 0, 0, 0);
    }
    if (step < 15) {
#pragma unroll
      for (int fi = 0; fi < 6; ++fi)
        bw[fi] = *(const f16x8*)(wp[fi] + (step + 1) * 32);
    }
    __syncthreads();
  }

#pragma unroll
  for (int fi = 0; fi < 6; ++fi) {
    const int gf = 6 * wid + fi;
    const int z = gf >> 3, fl = gf & 7;
    const float* bias = (z == 0) ? bqp : ((z == 1) ? bkp : bvp);
    const float bb = bias[fl * 16 + lo];
    if (z < 2) {
      u16* dst = qkv + (size_t)z * Mq * Uq;
      const float qs = (z == 0) ? LOG2E : 1.0f;
#pragma unroll
      for (int mg = 0; mg < 2; ++mg)
#pragma unroll
        for (int r = 0; r < 4; ++r) {
          const int m = mbase + 16 * mg + 4 * g + r;
          dst[(size_t)m * Uq + fl * 16 + lo] = f2h(fmaxf(acc[mg][fi][r] + bb, 0.f) * qs);
        }
    } else {
      u16* vT = qkv + (size_t)2 * Mq * Uq;   // vT[batch][n][s]
      const int n = fl * 16 + lo;
#pragma unroll
      for (int mg = 0; mg < 2; ++mg) {
        const int m0 = mbase + 16 * mg + 4 * g;
        const int bb_ = m0 >> 12, s0 = m0 & (Sq - 1);
        ushort4 pv = make_ushort4(f2h(fmaxf(acc[mg][fi][0] + bb, 0.f)),
                                  f2h(fmaxf(acc[mg][fi][1] + bb, 0.f)),
                                  f2h(fmaxf(acc[mg][fi][2] + bb, 0.f)),
                                  f2h(fmaxf(acc[mg][fi][3] + bb, 0.f)));
        *(ushort4*)(vT + (size_t)bb_ * Uq * Sq + (size_t)n * Sq + s0) = pv;
      }
    }
  }
}

// ---------------- flash attention partials (32x32 swapped QK^T, lane-local softmax) ----
// 4 warps x 32 q-rows (128 rows/block). KBLK=64. nsplit=4, grid 512 (best-known, R11).
// Counted vmcnt(4) at B1; raw v_exp_f32 for all exp2 (R15/R16's proven attn).
__global__ __launch_bounds__(256, 2) void attn_kernel(const u16* __restrict__ qkv,
                                                      u16* __restrict__ op,
                                                      float2* __restrict__ mlp,
                                                      int kvlen) {
  const int nb = gridDim.x;                  // 128 * nsplit
  const int bid = blockIdx.x;
  const int xcd = bid & 7, idx = bid >> 3;
  const int b = xcd >> 1;                    // batch pinned to 2 XCDs
  const int within = (xcd & 1) * (nb >> 3) + idx;   // [0, 32*nsplit)
  const int split = within >> 5, qblk = within & 31;
  const int kv0 = split * kvlen;
  const int kvrem = Sq - kv0;
  const int nit = ((kvrem < kvlen) ? kvrem : kvlen) >> 6;

  const int tid = threadIdx.x;
  const int wid = tid >> 6, lane = tid & 63;
  const int l32 = lane & 31, hi = lane >> 5;

  const u16* kbase = qkv + (size_t)Mq * Uq + (size_t)b * Sq * Uq;
  const u16* vbase = qkv + (size_t)2 * Mq * Uq + (size_t)b * Uq * Sq;

  __shared__ __align__(16) unsigned char kt[16384];       // 64 x 256B, XOR-swizzled
  __shared__ __align__(16) unsigned char vt[16384];       // 128 x 128B, XOR-swizzled
  __shared__ __align__(16) unsigned char plds[4][4096];   // per-wave P: 32 x 128B, swz
  __shared__ float smx[4][32];                            // per-warp broadcasts

  // K reg-staging: wave w covers rows [16w,16w+16); lane -> 4 x 16B
  const int s4 = lane >> 4, j16 = lane & 15;
  const char* kg = (const char*)kbase + (size_t)(kv0 + 16 * wid) * 256 + 16 * lane;
  const int kwo0 = (16 * wid + 0 + s4) * 256 + ((j16 ^ ((0 + s4) & 7)) << 4);
  const int kwo1 = (16 * wid + 4 + s4) * 256 + ((j16 ^ ((4 + s4) & 7)) << 4);
  const int kwo2 = (16 * wid + 8 + s4) * 256 + ((j16 ^ ((8 + s4) & 7)) << 4);
  const int kwo3 = (16 * wid + 12 + s4) * 256 + ((j16 ^ ((12 + s4) & 7)) << 4);

  // V gl_lds: wave w covers vT rows [32w,32w+32); source pre-swizzled
  const int s8 = lane >> 3, j8 = lane & 7;
  const int vo = s8 * 8192 + ((j8 ^ s8) << 4);
  const char* vgp = (const char*)vbase + (size_t)kv0 * 2 + (size_t)wid * 262144 + vo;
  char* const vl = (char*)vt + wid * 4096;

#define VSTAGE() do {                       \
    gl_lds16(vgp,          vl);             \
    gl_lds16(vgp + 65536,  vl + 1024);      \
    gl_lds16(vgp + 131072, vl + 2048);      \
    gl_lds16(vgp + 196608, vl + 3072);      \
  } while (0)
#define KLOAD() do {                        \
    ka0 = *(const uint4*)(kg + 0);          \
    ka1 = *(const uint4*)(kg + 1024);       \
    ka2 = *(const uint4*)(kg + 2048);       \
    ka3 = *(const uint4*)(kg + 3072);       \
    kg += 16384;                            \
  } while (0)
#define KWRITE() do {                       \
    *(uint4*)(&kt[kwo0]) = ka0;             \
    *(uint4*)(&kt[kwo1]) = ka1;             \
    *(uint4*)(&kt[kwo2]) = ka2;             \
    *(uint4*)(&kt[kwo3]) = ka3;             \
  } while (0)

  // Q frags (B operand of swapped 32x32 QK^T): q = qrow, k = 16*ks + 8*hi + j
  const int qrow = b * Sq + qblk * 128 + wid * 32 + l32;
  f16x8 qf[8];
#pragma unroll
  for (int ks = 0; ks < 8; ++ks)
    qf[ks] = *(const f16x8*)(qkv + (size_t)qrow * Uq + 16 * ks + 8 * hi);

  f32x16 acc4[4];
#pragma unroll
  for (int f = 0; f < 4; ++f) acc4[f] = (f32x16){};
  float m_run = -1e30f, l_run = 0.f;
  float* const smxw = &smx[wid][0];

  // plds bases: row = q = l32 (128B, 8 chunks of 16B), chunk XOR (l32&7)
  const int q7 = l32 & 7;
  char* const plw = (char*)plds + wid * 4096 + l32 * 128 + 8 * hi;    // write base
  const char* const plr = (const char*)plds + wid * 4096 + l32 * 128; // read base

  uint4 ka0, ka1, ka2, ka3;

  // ---- prologue ----
  VSTAGE();
  KLOAD();
  asm volatile("s_waitcnt vmcnt(0)" ::: "memory");
  KWRITE();
  if (nit > 1) KLOAD();
  asm volatile("s_waitcnt lgkmcnt(0)" ::: "memory");
  __builtin_amdgcn_sched_barrier(0);
  __builtin_amdgcn_s_barrier();
  __builtin_amdgcn_sched_barrier(0);

  for (int it = 0; it < nit; ++it) {
    // ---- QK^T (swapped, 32x32): lane owns q = l32 (full P-row across the hi-pair) ----
    f32x16 sf0 = (f32x16){}, sf1 = (f32x16){};
    __builtin_amdgcn_s_setprio(1);
#pragma unroll
    for (int ks = 0; ks < 8; ++ks) {
      const int co = ((2 * ks + hi) ^ q7) << 4;
      f16x8 a0 = *(const f16x8*)(&kt[l32 * 256 + co]);
      f16x8 a1 = *(const f16x8*)(&kt[(32 + l32) * 256 + co]);
      sf0 = __builtin_amdgcn_mfma_f32_32x32x16_f16(a0, qf[ks], sf0, 0, 0, 0);
      sf1 = __builtin_amdgcn_mfma_f32_32x32x16_f16(a1, qf[ks], sf1, 0, 0, 0);
    }
    __builtin_amdgcn_s_setprio(0);

    // ---- lane-local softmax (log2 domain); sf reg r <-> kv = (r&3)+8*(r>>2)+4*hi ----
    float t8[8];
#pragma unroll
    for (int i = 0; i < 8; ++i)
      t8[i] = fmaxf(fmaxf(sf0[i], sf0[i + 8]), fmaxf(sf1[i], sf1[i + 8]));
#pragma unroll
    for (int i = 0; i < 4; ++i) t8[i] = fmaxf(t8[i], t8[i + 4]);
    float tmax = fmaxf(fmaxf(t8[0], t8[1]), fmaxf(t8[2], t8[3]));
    tmax = xmax32(tmax);                      // combine hi/lo halves of the q-row

    if (__any(tmax > m_run + 8.f)) {          // T13 defer-max (rare)
      const float m_new = fmaxf(m_run, tmax);
      const float sc = EXP2(m_run - m_new);
      if (lane < 32) smxw[l32] = sc;
#pragma unroll
      for (int r = 0; r < 16; ++r) {
        const float scr = smxw[(r & 3) + 8 * (r >> 2) + 4 * hi];
#pragma unroll
        for (int f = 0; f < 4; ++f) acc4[f][r] *= scr;
      }
      l_run *= sc;
      m_run = m_new;
    }

    float psum = 0.f;
    unsigned Ap[2][4], Bp[2][4];
#pragma unroll
    for (int ks2 = 0; ks2 < 2; ++ks2) {
#pragma unroll
      for (int m = 0; m < 4; ++m) {
        const float s0v = ks2 ? sf1[4 * m + 0] : sf0[4 * m + 0];
        const float s1v = ks2 ? sf1[4 * m + 1] : sf0[4 * m + 1];
        const float s2v = ks2 ? sf1[4 * m + 2] : sf0[4 * m + 2];
        const float s3v = ks2 ? sf1[4 * m + 3] : sf0[4 * m + 3];
        const float p0 = EXP2(s0v - m_run), p1 = EXP2(s1v - m_run);
        const float p2 = EXP2(s2v - m_run), p3 = EXP2(s3v - m_run);
        psum += (p0 + p1) + (p2 + p3);
        Ap[ks2][m] = pk2(p0, p1);
        Bp[ks2][m] = pk2(p2, p3);
      }
    }
    l_run += xsum32(psum);

    // ---- P refragment via per-wave swizzled LDS roundtrip ----
#pragma unroll
    for (int ks2 = 0; ks2 < 2; ++ks2)
#pragma unroll
      for (int m = 0; m < 4; ++m) {
        const int c = 4 * ks2 + m;
        *(uint2*)(plw + ((c ^ q7) << 4)) = make_uint2(Ap[ks2][m], Bp[ks2][m]);
      }
    f16x8 pa[4];
#pragma unroll
    for (int ks2 = 0; ks2 < 2; ++ks2)
#pragma unroll
      for (int kk = 0; kk < 2; ++kk)
        pa[2 * ks2 + kk] =
            *(const f16x8*)(plr + (((4 * ks2 + 2 * kk + hi) ^ q7) << 4));

    // counted drain (T4): only V(it)'s 4 gl_lds must land; K(it+1) flies under PV
    if (it + 1 < nit) asm volatile("s_waitcnt vmcnt(4)" ::: "memory");
    else              asm volatile("s_waitcnt vmcnt(0)" ::: "memory");
    __builtin_amdgcn_sched_barrier(0);
    __builtin_amdgcn_s_barrier();                      // B1: V visible, kt QK reads done
    __builtin_amdgcn_sched_barrier(0);

    // ---- PV (32x32): O[q][d] += P[q][kv] * V[kv][d] ----
    __builtin_amdgcn_s_setprio(1);
#pragma unroll
    for (int ks = 0; ks < 4; ++ks) {
#pragma unroll
      for (int f = 0; f < 4; ++f) {
        const int d = 32 * f + l32;
        f16x8 bv = *(const f16x8*)(&vt[d * 128 + (((2 * ks + hi) ^ q7) << 4)]);
        acc4[f] = __builtin_amdgcn_mfma_f32_32x32x16_f16(pa[ks], bv, acc4[f], 0, 0, 0);
      }
    }
    __builtin_amdgcn_s_setprio(0);

    if (it + 1 < nit) KWRITE();            // K(it+1): regs -> kt (auto vmcnt wait on ka)
    asm volatile("s_waitcnt lgkmcnt(0)" ::: "memory");
    __builtin_amdgcn_sched_barrier(0);
    __builtin_amdgcn_s_barrier();          // B2: kt(it+1) visible, vt PV reads done
    __builtin_amdgcn_sched_barrier(0);

    if (it + 1 < nit) {
      vgp += 128;
      VSTAGE();                            // V(it+1) flies under next QK^T+softmax
      if (it + 2 < nit) KLOAD();           // K(it+2) -> regs
    }
  }
#undef VSTAGE
#undef KLOAD
#undef KWRITE

  // ---- write NORMALIZED fp16 partials + (m,l) ----
  if (lane < 32) smxw[l32] = 1.f / l_run;   // per-q reciprocal broadcast (same-wave LDS)
  const size_t rb = (size_t)split * Mq + (size_t)b * Sq + qblk * 128 + wid * 32;
  if (lane < 32) mlp[rb + lane] = make_float2(m_run, l_run);
  u16* od = op + rb * Uq;
#pragma unroll
  for (int f = 0; f < 4; ++f)
#pragma unroll
    for (int r = 0; r < 16; ++r) {
      const int qr = (r & 3) + 8 * (r >> 2) + 4 * hi;
      od[(size_t)qr * Uq + 32 * f + l32] = f2h(acc4[f][r] * smxw[qr]);
    }
}

// ---------------- combine kv-split partials (log2 domain, fp16 normalized) ----------------
__global__ __launch_bounds__(256) void combine_kernel(const u16* __restrict__ op,
                                                      const float2* __restrict__ mlp,
                                                      float* __restrict__ out,
                                                      int nsplit) {
  const int idx = blockIdx.x * 256 + threadIdx.x;
  const int q = idx >> 5, nq = idx & 31;
  float M = -1e30f;
  for (int s = 0; s < nsplit; ++s) M = fmaxf(M, mlp[(size_t)s * Mq + q].x);
  float L = 0.f;
  float ox = 0.f, oy = 0.f, oz = 0.f, ow = 0.f;
  for (int s = 0; s < nsplit; ++s) {
    const float2 ml = mlp[(size_t)s * Mq + q];
    const float w = EXP2(ml.x - M) * ml.y;   // weight = exp2(m-M) * l
    L += w;
    const ushort4 v = *(const ushort4*)(op + ((size_t)s * Mq + q) * Uq + nq * 4);
    ox += w * h2f(v.x); oy += w * h2f(v.y); oz += w * h2f(v.z); ow += w * h2f(v.w);
  }
  const float inv = 1.f / L;
  *(float4*)(out + (size_t)q * Uq + nq * 4) = make_float4(ox * inv, oy * inv, oz * inv, ow * inv);
}

extern "C" void kernel_launch(void* const* d_in, const int* in_sizes, int n_in,
                              void* d_out, int out_size, void* d_ws, size_t ws_size,
                              hipStream_t stream) {
  const float* X   = (const float*)d_in[0];
  const float* Wqp = (const float*)d_in[1];
  const float* bqp = (const float*)d_in[2];
  const float* Wkp = (const float*)d_in[3];
  const float* bkp = (const float*)d_in[4];
  const float* Wvp = (const float*)d_in[5];
  const float* bvp = (const float*)d_in[6];
  float* out = (float*)d_out;

  u16* qkv = (u16*)d_ws;                                   // q(4MB) k(4MB) vT(4MB) fp16
  u16* wt  = qkv + (size_t)3 * Mq * Uq;                    // 3 x [128][512] fp16
  u16* op  = wt + 3 * 65536;                               // normalized fp16 partials

  const size_t base = (size_t)12976128;                    // qkv + wt bytes
  const size_t per  = (size_t)(Mq * Uq * 2 + Mq * 8);      // 4.19MB op + 1MB mlp
  int nsplit = 4;                                          // grid 512 = best-known (R11)
  if (ws_size < base + 4 * per) nsplit = 2;
  if (ws_size < base + 2 * per) nsplit = 1;
  float2* mlp = (float2*)(op + (size_t)nsplit * Mq * Uq);
  const int kvlen = Sq / nsplit;

  wt_kernel<<<768, 256, 0, stream>>>(Wqp, Wkp, Wvp, wt);
  proj_kernel<<<Mq / 32, 256, 0, stream>>>(X, wt, bqp, bkp, bvp, qkv);
  attn_kernel<<<128 * nsplit, 256, 0, stream>>>(qkv, op, mlp, kvlen);
  combine_kernel<<<(Mq * 32) / 256, 256, 0, stream>>>(op, mlp, out, nsplit);
}

// Round 20
// 86.142 us; speedup vs baseline: 1.1611x; 1.0146x over previous
//
#include <hip/hip_runtime.h>
#include <stdint.h>

#define Bq 4
#define Sq 4096
#define DIN 512
#define Uq 128
#define Mq (Bq * Sq)
#define LOG2E 1.44269504f

typedef __attribute__((ext_vector_type(8))) _Float16 f16x8;
typedef __attribute__((ext_vector_type(4))) float f32x4;
typedef __attribute__((ext_vector_type(16))) float f32x16;
typedef unsigned short u16;

__device__ __forceinline__ u16 f2h(float f) {
  union { _Float16 h; u16 u; } v;
  v.h = (_Float16)f;
  return v.u;
}
__device__ __forceinline__ float h2f(u16 u) {
  union { u16 u; _Float16 h; } v;
  v.u = u;
  return (float)v.h;
}
__device__ __forceinline__ unsigned pk2(float a, float b) {
  return __builtin_bit_cast(unsigned, __builtin_amdgcn_cvt_pkrtz(a, b));
}
__device__ __forceinline__ void gl_lds16(const void* g, void* l) {
  __builtin_amdgcn_global_load_lds(
      (const __attribute__((address_space(1))) unsigned int*)g,
      (__attribute__((address_space(3))) unsigned int*)l, 16, 0, 0);
}
__device__ __forceinline__ float xmax32(float v) { return fmaxf(v, __shfl_xor(v, 32)); }
__device__ __forceinline__ float xsum32(float v) { return v + __shfl_xor(v, 32); }

// raw v_exp_f32 (args bounded: <= +8 by defer-max; large-negative underflows to 0)
#if defined(__has_builtin) && __has_builtin(__builtin_amdgcn_exp2f)
#define EXP2(x) __builtin_amdgcn_exp2f(x)
#else
#define EXP2(x) exp2f(x)
#endif

// ---------------- W transpose: W[512][128] f32 -> Wt[128][512] fp16 ----------------
__global__ __launch_bounds__(256) void wt_kernel(const float* __restrict__ Wqp,
                                                 const float* __restrict__ Wkp,
                                                 const float* __restrict__ Wvp,
                                                 u16* __restrict__ wt) {
  int idx = blockIdx.x * 256 + threadIdx.x;
  int z = idx >> 16, r = idx & 65535;
  int n = r >> 9, k = r & 511;
  const float* W = (z == 0) ? Wqp : ((z == 1) ? Wkp : Wvp);
  wt[idx] = f2h(W[k * Uq + n]);
}

// ------------- fused QKV projection + ReLU -> fp16 (q scaled by log2e) -------------
// 32-row m-tiles, grid 512 (2 blocks/CU), 4 waves; wave w owns 6 global f-cols
// gf in [6w,6w+6). B-frags reg-prefetched one step ahead. (R14/R16's proven version.)
__global__ __launch_bounds__(256, 2) void proj_kernel(const float* __restrict__ X,
                                                      const u16* __restrict__ Wt,
                                                      const float* __restrict__ bqp,
                                                      const float* __restrict__ bkp,
                                                      const float* __restrict__ bvp,
                                                      u16* __restrict__ qkv) {
  const int mbase = blockIdx.x * 32;
  const int tid = threadIdx.x;
  const int wid = tid >> 6, lane = tid & 63;
  const int lo = lane & 15, g = lane >> 4;

  __shared__ __align__(16) u16 xt[32][40];

  f32x4 acc[2][6];
#pragma unroll
  for (int mg = 0; mg < 2; ++mg)
#pragma unroll
    for (int fi = 0; fi < 6; ++fi) acc[mg][fi] = (f32x4){0.f, 0.f, 0.f, 0.f};

  const int xrow = tid >> 2, xcc = (tid & 3) * 8;
  const float* xsrc = X + (size_t)(mbase + xrow) * DIN + xcc;
  float4 nv0, nv1;
  if (tid < 128) {
    nv0 = *(const float4*)xsrc;
    nv1 = *(const float4*)(xsrc + 4);
  }

  const u16* wp[6];
#pragma unroll
  for (int fi = 0; fi < 6; ++fi) {
    const int gf = 6 * wid + fi;
    const int R = (gf >> 3) * 128 + (gf & 7) * 16 + lo;
    wp[fi] = Wt + (size_t)R * 512 + 8 * g;
  }
  f16x8 bw[6];
#pragma unroll
  for (int fi = 0; fi < 6; ++fi) bw[fi] = *(const f16x8*)(wp[fi]);

  for (int step = 0; step < 16; ++step) {
    if (tid < 128) {
      union { u16 u[8]; uint4 v; } pk;
      pk.u[0] = f2h(nv0.x); pk.u[1] = f2h(nv0.y); pk.u[2] = f2h(nv0.z); pk.u[3] = f2h(nv0.w);
      pk.u[4] = f2h(nv1.x); pk.u[5] = f2h(nv1.y); pk.u[6] = f2h(nv1.z); pk.u[7] = f2h(nv1.w);
      *(uint4*)(&xt[xrow][xcc]) = pk.v;
    }
    __syncthreads();
    if (step < 15 && tid < 128) {
      const float* s2 = xsrc + (step + 1) * 32;
      nv0 = *(const float4*)s2;
      nv1 = *(const float4*)(s2 + 4);
    }
    f16x8 a0 = *(const f16x8*)(&xt[lo][8 * g]);
    f16x8 a1 = *(const f16x8*)(&xt[16 + lo][8 * g]);
#pragma unroll
    for (int fi = 0; fi < 6; ++fi) {
      acc[0][fi] = __builtin_amdgcn_mfma_f32_16x16x32_f16(a0, bw[fi], acc[0][fi], 0, 0, 0);
      acc[1][fi] = __builtin_amdgcn_mfma_f32_16x16x32_f16(a1, bw[fi], acc[1][fi], 0, 0, 0);
    }
    if (step < 15) {
#pragma unroll
      for (int fi = 0; fi < 6; ++fi)
        bw[fi] = *(const f16x8*)(wp[fi] + (step + 1) * 32);
    }
    __syncthreads();
  }

#pragma unroll
  for (int fi = 0; fi < 6; ++fi) {
    const int gf = 6 * wid + fi;
    const int z = gf >> 3, fl = gf & 7;
    const float* bias = (z == 0) ? bqp : ((z == 1) ? bkp : bvp);
    const float bb = bias[fl * 16 + lo];
    if (z < 2) {
      u16* dst = qkv + (size_t)z * Mq * Uq;
      const float qs = (z == 0) ? LOG2E : 1.0f;
#pragma unroll
      for (int mg = 0; mg < 2; ++mg)
#pragma unroll
        for (int r = 0; r < 4; ++r) {
          const int m = mbase + 16 * mg + 4 * g + r;
          dst[(size_t)m * Uq + fl * 16 + lo] = f2h(fmaxf(acc[mg][fi][r] + bb, 0.f) * qs);
        }
    } else {
      u16* vT = qkv + (size_t)2 * Mq * Uq;   // vT[batch][n][s]
      const int n = fl * 16 + lo;
#pragma unroll
      for (int mg = 0; mg < 2; ++mg) {
        const int m0 = mbase + 16 * mg + 4 * g;
        const int bb_ = m0 >> 12, s0 = m0 & (Sq - 1);
        ushort4 pv = make_ushort4(f2h(fmaxf(acc[mg][fi][0] + bb, 0.f)),
                                  f2h(fmaxf(acc[mg][fi][1] + bb, 0.f)),
                                  f2h(fmaxf(acc[mg][fi][2] + bb, 0.f)),
                                  f2h(fmaxf(acc[mg][fi][3] + bb, 0.f)));
        *(ushort4*)(vT + (size_t)bb_ * Uq * Sq + (size_t)n * Sq + s0) = pv;
      }
    }
  }
}

// ---------------- flash attention partials (32x32 swapped QK^T, lane-local softmax) ----
// 4 warps x 32 q-rows (128 rows/block). KBLK=64. nsplit=4, grid 512.
// P refragment fully IN-REGISTER via shfl_xor(32) (plds deleted: -12 4-way-conflicted
// LDS ops/iter, -16KB LDS). Counted vmcnt(4) at B1; raw v_exp_f32.
__global__ __launch_bounds__(256, 2) void attn_kernel(const u16* __restrict__ qkv,
                                                      u16* __restrict__ op,
                                                      float2* __restrict__ mlp,
                                                      int kvlen) {
  const int nb = gridDim.x;                  // 128 * nsplit
  const int bid = blockIdx.x;
  const int xcd = bid & 7, idx = bid >> 3;
  const int b = xcd >> 1;                    // batch pinned to 2 XCDs
  const int within = (xcd & 1) * (nb >> 3) + idx;   // [0, 32*nsplit)
  const int split = within >> 5, qblk = within & 31;
  const int kv0 = split * kvlen;
  const int kvrem = Sq - kv0;
  const int nit = ((kvrem < kvlen) ? kvrem : kvlen) >> 6;

  const int tid = threadIdx.x;
  const int wid = tid >> 6, lane = tid & 63;
  const int l32 = lane & 31, hi = lane >> 5;

  const u16* kbase = qkv + (size_t)Mq * Uq + (size_t)b * Sq * Uq;
  const u16* vbase = qkv + (size_t)2 * Mq * Uq + (size_t)b * Uq * Sq;

  __shared__ __align__(16) unsigned char kt[16384];       // 64 x 256B, XOR-swizzled
  __shared__ __align__(16) unsigned char vt[16384];       // 128 x 128B, XOR-swizzled
  __shared__ float smx[4][32];                            // per-warp broadcasts

  // K reg-staging: wave w covers rows [16w,16w+16); lane -> 4 x 16B
  const int s4 = lane >> 4, j16 = lane & 15;
  const char* kg = (const char*)kbase + (size_t)(kv0 + 16 * wid) * 256 + 16 * lane;
  const int kwo0 = (16 * wid + 0 + s4) * 256 + ((j16 ^ ((0 + s4) & 7)) << 4);
  const int kwo1 = (16 * wid + 4 + s4) * 256 + ((j16 ^ ((4 + s4) & 7)) << 4);
  const int kwo2 = (16 * wid + 8 + s4) * 256 + ((j16 ^ ((8 + s4) & 7)) << 4);
  const int kwo3 = (16 * wid + 12 + s4) * 256 + ((j16 ^ ((12 + s4) & 7)) << 4);

  // V gl_lds: wave w covers vT rows [32w,32w+32); source pre-swizzled
  const int s8 = lane >> 3, j8 = lane & 7;
  const int vo = s8 * 8192 + ((j8 ^ s8) << 4);
  const char* vgp = (const char*)vbase + (size_t)kv0 * 2 + (size_t)wid * 262144 + vo;
  char* const vl = (char*)vt + wid * 4096;

#define VSTAGE() do {                       \
    gl_lds16(vgp,          vl);             \
    gl_lds16(vgp + 65536,  vl + 1024);      \
    gl_lds16(vgp + 131072, vl + 2048);      \
    gl_lds16(vgp + 196608, vl + 3072);      \
  } while (0)
#define KLOAD() do {                        \
    ka0 = *(const uint4*)(kg + 0);          \
    ka1 = *(const uint4*)(kg + 1024);       \
    ka2 = *(const uint4*)(kg + 2048);       \
    ka3 = *(const uint4*)(kg + 3072);       \
    kg += 16384;                            \
  } while (0)
#define KWRITE() do {                       \
    *(uint4*)(&kt[kwo0]) = ka0;             \
    *(uint4*)(&kt[kwo1]) = ka1;             \
    *(uint4*)(&kt[kwo2]) = ka2;             \
    *(uint4*)(&kt[kwo3]) = ka3;             \
  } while (0)

  // Q frags (B operand of swapped 32x32 QK^T): q = qrow, k = 16*ks + 8*hi + j
  const int qrow = b * Sq + qblk * 128 + wid * 32 + l32;
  f16x8 qf[8];
#pragma unroll
  for (int ks = 0; ks < 8; ++ks)
    qf[ks] = *(const f16x8*)(qkv + (size_t)qrow * Uq + 16 * ks + 8 * hi);

  f32x16 acc4[4];
#pragma unroll
  for (int f = 0; f < 4; ++f) acc4[f] = (f32x16){};
  float m_run = -1e30f, l_run = 0.f;
  float* const smxw = &smx[wid][0];

  const int q7 = l32 & 7;

  uint4 ka0, ka1, ka2, ka3;

  // ---- prologue ----
  VSTAGE();
  KLOAD();
  asm volatile("s_waitcnt vmcnt(0)" ::: "memory");
  KWRITE();
  if (nit > 1) KLOAD();
  asm volatile("s_waitcnt lgkmcnt(0)" ::: "memory");
  __builtin_amdgcn_sched_barrier(0);
  __builtin_amdgcn_s_barrier();
  __builtin_amdgcn_sched_barrier(0);

  for (int it = 0; it < nit; ++it) {
    // ---- QK^T (swapped, 32x32): lane owns q = l32 (full P-row across the hi-pair) ----
    f32x16 sf0 = (f32x16){}, sf1 = (f32x16){};
    __builtin_amdgcn_s_setprio(1);
#pragma unroll
    for (int ks = 0; ks < 8; ++ks) {
      const int co = ((2 * ks + hi) ^ q7) << 4;
      f16x8 a0 = *(const f16x8*)(&kt[l32 * 256 + co]);
      f16x8 a1 = *(const f16x8*)(&kt[(32 + l32) * 256 + co]);
      sf0 = __builtin_amdgcn_mfma_f32_32x32x16_f16(a0, qf[ks], sf0, 0, 0, 0);
      sf1 = __builtin_amdgcn_mfma_f32_32x32x16_f16(a1, qf[ks], sf1, 0, 0, 0);
    }
    __builtin_amdgcn_s_setprio(0);

    // ---- lane-local softmax (log2 domain); sf reg r <-> kv = (r&3)+8*(r>>2)+4*hi ----
    float t8[8];
#pragma unroll
    for (int i = 0; i < 8; ++i)
      t8[i] = fmaxf(fmaxf(sf0[i], sf0[i + 8]), fmaxf(sf1[i], sf1[i + 8]));
#pragma unroll
    for (int i = 0; i < 4; ++i) t8[i] = fmaxf(t8[i], t8[i + 4]);
    float tmax = fmaxf(fmaxf(t8[0], t8[1]), fmaxf(t8[2], t8[3]));
    tmax = xmax32(tmax);                      // combine hi/lo halves of the q-row

    if (__any(tmax > m_run + 8.f)) {          // T13 defer-max (rare)
      const float m_new = fmaxf(m_run, tmax);
      const float sc = EXP2(m_run - m_new);
      if (lane < 32) smxw[l32] = sc;
#pragma unroll
      for (int r = 0; r < 16; ++r) {
        const float scr = smxw[(r & 3) + 8 * (r >> 2) + 4 * hi];
#pragma unroll
        for (int f = 0; f < 4; ++f) acc4[f][r] *= scr;
      }
      l_run *= sc;
      m_run = m_new;
    }

    float psum = 0.f;
    unsigned Ap[2][4], Bp[2][4];
#pragma unroll
    for (int ks2 = 0; ks2 < 2; ++ks2) {
#pragma unroll
      for (int m = 0; m < 4; ++m) {
        const float s0v = ks2 ? sf1[4 * m + 0] : sf0[4 * m + 0];
        const float s1v = ks2 ? sf1[4 * m + 1] : sf0[4 * m + 1];
        const float s2v = ks2 ? sf1[4 * m + 2] : sf0[4 * m + 2];
        const float s3v = ks2 ? sf1[4 * m + 3] : sf0[4 * m + 3];
        const float p0 = EXP2(s0v - m_run), p1 = EXP2(s1v - m_run);
        const float p2 = EXP2(s2v - m_run), p3 = EXP2(s3v - m_run);
        psum += (p0 + p1) + (p2 + p3);
        Ap[ks2][m] = pk2(p0, p1);             // kv {8m+4hi+0,1} (+32*ks2)
        Bp[ks2][m] = pk2(p2, p3);             // kv {8m+4hi+2,3}
      }
    }
    l_run += xsum32(psum);

    // ---- P refragment IN-REGISTER via shfl_xor(32) (verified both hi cases) ----
    // lane(hi) needs own + partner's (Ap,Bp)[ks2][2kk+hi]; send [2kk+(1-hi)].
    f16x8 pa[4];
#pragma unroll
    for (int ks2 = 0; ks2 < 2; ++ks2)
#pragma unroll
      for (int kk = 0; kk < 2; ++kk) {
        const unsigned sa = hi ? Ap[ks2][2 * kk] : Ap[ks2][2 * kk + 1];
        const unsigned sb = hi ? Bp[ks2][2 * kk] : Bp[ks2][2 * kk + 1];
        const unsigned xa = (unsigned)__shfl_xor((int)sa, 32);
        const unsigned xb = (unsigned)__shfl_xor((int)sb, 32);
        const unsigned oa = hi ? Ap[ks2][2 * kk + 1] : Ap[ks2][2 * kk];
        const unsigned ob = hi ? Bp[ks2][2 * kk + 1] : Bp[ks2][2 * kk];
        union { unsigned u[4]; f16x8 v; } w;
        w.u[0] = hi ? xa : oa;
        w.u[1] = hi ? xb : ob;
        w.u[2] = hi ? oa : xa;
        w.u[3] = hi ? ob : xb;
        pa[2 * ks2 + kk] = w.v;
      }

    // counted drain (T4): only V(it)'s 4 gl_lds must land; K(it+1) flies under PV
    if (it + 1 < nit) asm volatile("s_waitcnt vmcnt(4)" ::: "memory");
    else              asm volatile("s_waitcnt vmcnt(0)" ::: "memory");
    __builtin_amdgcn_sched_barrier(0);
    __builtin_amdgcn_s_barrier();                      // B1: V visible, kt QK reads done
    __builtin_amdgcn_sched_barrier(0);

    // ---- PV (32x32): O[q][d] += P[q][kv] * V[kv][d] ----
    __builtin_amdgcn_s_setprio(1);
#pragma unroll
    for (int ks = 0; ks < 4; ++ks) {
#pragma unroll
      for (int f = 0; f < 4; ++f) {
        const int d = 32 * f + l32;
        f16x8 bv = *(const f16x8*)(&vt[d * 128 + (((2 * ks + hi) ^ q7) << 4)]);
        acc4[f] = __builtin_amdgcn_mfma_f32_32x32x16_f16(pa[ks], bv, acc4[f], 0, 0, 0);
      }
    }
    __builtin_amdgcn_s_setprio(0);

    if (it + 1 < nit) KWRITE();            // K(it+1): regs -> kt (auto vmcnt wait on ka)
    asm volatile("s_waitcnt lgkmcnt(0)" ::: "memory");
    __builtin_amdgcn_sched_barrier(0);
    __builtin_amdgcn_s_barrier();          // B2: kt(it+1) visible, vt PV reads done
    __builtin_amdgcn_sched_barrier(0);

    if (it + 1 < nit) {
      vgp += 128;
      VSTAGE();                            // V(it+1) flies under next QK^T+softmax
      if (it + 2 < nit) KLOAD();           // K(it+2) -> regs
    }
  }
#undef VSTAGE
#undef KLOAD
#undef KWRITE

  // ---- write NORMALIZED fp16 partials + (m,l) ----
  if (lane < 32) smxw[l32] = 1.f / l_run;   // per-q reciprocal broadcast (same-wave LDS)
  const size_t rb = (size_t)split * Mq + (size_t)b * Sq + qblk * 128 + wid * 32;
  if (lane < 32) mlp[rb + lane] = make_float2(m_run, l_run);
  u16* od = op + rb * Uq;
#pragma unroll
  for (int f = 0; f < 4; ++f)
#pragma unroll
    for (int r = 0; r < 16; ++r) {
      const int qr = (r & 3) + 8 * (r >> 2) + 4 * hi;
      od[(size_t)qr * Uq + 32 * f + l32] = f2h(acc4[f][r] * smxw[qr]);
    }
}

// ---------------- combine kv-split partials (log2 domain, fp16 normalized) ----------------
__global__ __launch_bounds__(256) void combine_kernel(const u16* __restrict__ op,
                                                      const float2* __restrict__ mlp,
                                                      float* __restrict__ out,
                                                      int nsplit) {
  const int idx = blockIdx.x * 256 + threadIdx.x;
  const int q = idx >> 5, nq = idx & 31;
  float M = -1e30f;
  for (int s = 0; s < nsplit; ++s) M = fmaxf(M, mlp[(size_t)s * Mq + q].x);
  float L = 0.f;
  float ox = 0.f, oy = 0.f, oz = 0.f, ow = 0.f;
  for (int s = 0; s < nsplit; ++s) {
    const float2 ml = mlp[(size_t)s * Mq + q];
    const float w = EXP2(ml.x - M) * ml.y;   // weight = exp2(m-M) * l
    L += w;
    const ushort4 v = *(const ushort4*)(op + ((size_t)s * Mq + q) * Uq + nq * 4);
    ox += w * h2f(v.x); oy += w * h2f(v.y); oz += w * h2f(v.z); ow += w * h2f(v.w);
  }
  const float inv = 1.f / L;
  *(float4*)(out + (size_t)q * Uq + nq * 4) = make_float4(ox * inv, oy * inv, oz * inv, ow * inv);
}

extern "C" void kernel_launch(void* const* d_in, const int* in_sizes, int n_in,
                              void* d_out, int out_size, void* d_ws, size_t ws_size,
                              hipStream_t stream) {
  const float* X   = (const float*)d_in[0];
  const float* Wqp = (const float*)d_in[1];
  const float* bqp = (const float*)d_in[2];
  const float* Wkp = (const float*)d_in[3];
  const float* bkp = (const float*)d_in[4];
  const float* Wvp = (const float*)d_in[5];
  const float* bvp = (const float*)d_in[6];
  float* out = (float*)d_out;

  u16* qkv = (u16*)d_ws;                                   // q(4MB) k(4MB) vT(4MB) fp16
  u16* wt  = qkv + (size_t)3 * Mq * Uq;                    // 3 x [128][512] fp16
  u16* op  = wt + 3 * 65536;                               // normalized fp16 partials

  const size_t base = (size_t)12976128;                    // qkv + wt bytes
  const size_t per  = (size_t)(Mq * Uq * 2 + Mq * 8);      // 4.19MB op + 1MB mlp
  int nsplit = 4;                                          // grid 512 = best-known
  if (ws_size < base + 4 * per) nsplit = 2;
  if (ws_size < base + 2 * per) nsplit = 1;
  float2* mlp = (float2*)(op + (size_t)nsplit * Mq * Uq);
  const int kvlen = Sq / nsplit;

  wt_kernel<<<768, 256, 0, stream>>>(Wqp, Wkp, Wvp, wt);
  proj_kernel<<<Mq / 32, 256, 0, stream>>>(X, wt, bqp, bkp, bvp, qkv);
  attn_kernel<<<128 * nsplit, 256, 0, stream>>>(qkv, op, mlp, kvlen);
  combine_kernel<<<(Mq * 32) / 256, 256, 0, stream>>>(op, mlp, out, nsplit);
}